// Round 12
// baseline (549.001 us; speedup 1.0000x reference)
//
#include <hip/hip_runtime.h>
#include <hip/hip_bf16.h>

typedef __bf16 bf16_t;
typedef __bf16 bf16x8 __attribute__((ext_vector_type(8)));
typedef __bf16 bf16x4 __attribute__((ext_vector_type(4)));
typedef float f32x4 __attribute__((ext_vector_type(4)));

#define S_LEN 2048
#define HID   2048
#define NH    16
#define HD    128
#define QKVN  2304   // 2048 + 2*128
#define NEG_BIG (-30000.0f)
#define RESCALE_THR 8.0f

// direct global->LDS DMA, 16B per lane. lds dst must be the WAVE-UNIFORM base;
// HW adds lane*16 itself (m104). No LDS padding allowed in the covered range.
__device__ __forceinline__ void gld_lds16(const bf16_t* g, bf16_t* l) {
  __builtin_amdgcn_global_load_lds(
      (const __attribute__((address_space(1))) void*)((const void*)g),
      (__attribute__((address_space(3))) void*)((void*)l), 16, 0, 0);
}

// ---------------------------------------------------------------------------
// Fused prep: fp32->bf16 downcast of hidden states + both weight transposes.
// (verified round 10)
// ---------------------------------------------------------------------------
__device__ __forceinline__ void transpose_cvt_body(
    const float* __restrict__ in, bf16_t* __restrict__ out,
    int K, int N, int bx, int by, int tid)
{
  int nc = tid & 63;
  int kg = tid >> 6;
  int n  = bx * 64 + nc;
  int kb = by * 32 + kg * 8;
  bf16x8 v;
  #pragma unroll
  for (int i = 0; i < 8; ++i) v[i] = (bf16_t)in[(size_t)(kb + i) * N + n];
  *(bf16x8*)(out + (size_t)n * K + kb) = v;
}

__global__ __launch_bounds__(256) void prep_kernel(
    const float* __restrict__ hidden, bf16_t* __restrict__ hbf,
    const float* __restrict__ wq, bf16_t* __restrict__ wqT,
    const float* __restrict__ wp, bf16_t* __restrict__ wpT)
{
  const int id  = blockIdx.x;
  const int tid = threadIdx.x;
  if (id < 8192) {
    int i = (id * 256 + tid) * 4;
    float4 v = *(const float4*)(hidden + i);
    bf16x4 o;
    o[0] = (bf16_t)v.x; o[1] = (bf16_t)v.y; o[2] = (bf16_t)v.z; o[3] = (bf16_t)v.w;
    *(bf16x4*)(hbf + i) = o;
  } else if (id < 8192 + 2304) {
    int id2 = id - 8192;
    transpose_cvt_body(wq, wqT, HID, QKVN, id2 % 36, id2 / 36, tid);
  } else {
    int id2 = id - 10496;
    transpose_cvt_body(wp, wpT, HID, HID, id2 % 32, id2 / 32, tid);
  }
}

// ---------------------------------------------------------------------------
// Extract V^T from qkv: vtg[b][d][s] = qkv[b*S+s][2176+d]. (verified)
// ---------------------------------------------------------------------------
__global__ __launch_bounds__(256) void vt_extract_kernel(
    const bf16_t* __restrict__ qkv, bf16_t* __restrict__ vtg)
{
  int d  = threadIdx.x & 127;
  int sg = threadIdx.x >> 7;
  int b  = blockIdx.y;
  int s8 = blockIdx.x * 2 + sg;
  bf16x8 v;
  #pragma unroll
  for (int i = 0; i < 8; ++i)
    v[i] = qkv[((size_t)(b * S_LEN + s8 * 8 + i)) * QKVN + HID + HD + d];
  *(bf16x8*)(vtg + ((size_t)(b * HD + d)) * S_LEN + s8 * 8) = v;
}

// ---------------------------------------------------------------------------
// GEMM: C[M,N] = A[M,K] @ WT^T + bias (WT pre-transposed [N][K]).
// 128x64 C-tile, 4 waves as 2x2 (wave 64x32), BK=64, 1-barrier dbuf DMA
// schedule, T1 XCD swizzle. (r11 config — at the plain-HIP 2-phase
// structural level for this shape; parked.)
// ---------------------------------------------------------------------------
template <typename OutT>
__global__ __launch_bounds__(256, 3) void gemm_bias_kernel(
    const bf16_t* __restrict__ A, const bf16_t* __restrict__ WT,
    const float* __restrict__ bias, OutT* __restrict__ C,
    int K, int lda, int ldc)
{
  __shared__ bf16_t Ash[2 * 128 * 64];   // [buf][m][k] swizzled, NO padding
  __shared__ bf16_t Bsh[2 * 64 * 64];    // [buf][n][k] swizzled, NO padding

  const int tid  = threadIdx.x;
  const int wave = tid >> 6;
  const int lane = tid & 63;
  const int quad = lane >> 4;
  const int c16  = lane & 15;
  const int wm = wave >> 1;          // 0..1 : 64-row half
  const int wn = wave & 1;           // 0..1 : 32-col half

  // T1 XCD swizzle: id -> (id%8)*cpx + id/8, bijective when nwg%8==0.
  int id  = (int)(blockIdx.y * gridDim.x + blockIdx.x);
  int nwg = (int)(gridDim.x * gridDim.y);
  int swz = (nwg & 7) ? id : ((id & 7) * (nwg >> 3) + (id >> 3));
  const int n0 = (swz % (int)gridDim.x) * 64;
  const int m0 = (swz / (int)gridDim.x) * 128;

  f32x4 acc[4][2] = {};

  #define GSTAGE(bufi, k0v) do {                                             \
    bf16_t* Ad_ = Ash + (bufi) * 8192;                                       \
    bf16_t* Bd_ = Bsh + (bufi) * 4096;                                       \
    _Pragma("unroll")                                                        \
    for (int j_ = 0; j_ < 4; ++j_) {                                         \
      int c_ = tid + j_ * 256;                                               \
      int row_ = c_ >> 3;                                                    \
      int kcl_ = (c_ ^ row_) & 7;                                            \
      gld_lds16(A + (size_t)(m0 + row_) * lda + (k0v) + kcl_ * 8,            \
                Ad_ + (c_ & ~63) * 8);                                       \
    }                                                                        \
    _Pragma("unroll")                                                        \
    for (int j_ = 0; j_ < 2; ++j_) {                                         \
      int c_ = tid + j_ * 256;                                               \
      int row_ = c_ >> 3;                                                    \
      int kcl_ = (c_ ^ row_) & 7;                                            \
      gld_lds16(WT + (size_t)(n0 + row_) * K + (k0v) + kcl_ * 8,             \
                Bd_ + (c_ & ~63) * 8);                                       \
    }                                                                        \
  } while (0)

  GSTAGE(0, 0);
  int cur = 0;

  for (int k0 = 0; k0 < K; k0 += 64) {
    __syncthreads();
    if (k0 + 64 < K) GSTAGE(cur ^ 1, k0 + 64);

    const bf16_t* Ac = Ash + cur * 8192;
    const bf16_t* Bc = Bsh + cur * 4096;
    #pragma unroll
    for (int kk = 0; kk < 2; ++kk) {
      bf16x8 af[4], bfr[2];
      #pragma unroll
      for (int rb = 0; rb < 4; ++rb) {
        int row = wm * 64 + rb * 16 + c16;
        int kcp = ((kk * 4 + quad) ^ row) & 7;
        af[rb] = *(const bf16x8*)(Ac + row * 64 + kcp * 8);
      }
      #pragma unroll
      for (int nt = 0; nt < 2; ++nt) {
        int row = wn * 32 + nt * 16 + c16;
        int kcp = ((kk * 4 + quad) ^ row) & 7;
        bfr[nt] = *(const bf16x8*)(Bc + row * 64 + kcp * 8);
      }
      #pragma unroll
      for (int rb = 0; rb < 4; ++rb)
        #pragma unroll
        for (int nt = 0; nt < 2; ++nt)
          acc[rb][nt] = __builtin_amdgcn_mfma_f32_16x16x32_bf16(af[rb], bfr[nt],
                                                                acc[rb][nt], 0, 0, 0);
    }
    cur ^= 1;
  }
  #undef GSTAGE

  #pragma unroll
  for (int nt = 0; nt < 2; ++nt) {
    int col = n0 + wn * 32 + nt * 16 + c16;
    float bv = bias[col];
    #pragma unroll
    for (int rb = 0; rb < 4; ++rb) {
      int rbase = m0 + wm * 64 + rb * 16 + quad * 4;
      #pragma unroll
      for (int r = 0; r < 4; ++r)
        C[(size_t)(rbase + r) * ldc + col] = (OutT)(acc[rb][nt][r] + bv);
    }
  }
}

// ---------------------------------------------------------------------------
// Causal MQA attention, S^T formulation, QBLK=128, 8 waves, KVBLK=32.
//
// Round-12: occupancy push. r11 counters (MfmaUtil 19 + VALU 40 + LDS/trans
// issue, Occupancy 27%) say the SIMD ISSUE PORT is the shared resource and
// only ~2 waves/SIMD feed it (2 blocks/CU, degraded by pair-imbalance
// tails). KVBLK 64->32 cuts LDS 80->40 KB -> 4 blocks/CU (32 waves/CU):
//   K[2][32][128] 16K + VT[2][128][32] 16K + P[128][32] 8K = 40960 B.
// Same verified r7 schedule (single __syncthreads/tile + DMA prefetch),
// same XOR-involution swizzles with constants re-derived for 4-chunk rows
// (V,P: ^(r&3)); sacc [4]->[2]; launch_bounds(512,8) caps VGPR at 64.
// Barrier count doubles but 4 co-resident blocks overlap the drains; per-
// tile staged-bytes/MFMA ratio unchanged. T13 + T5 + pairing kept.
// ---------------------------------------------------------------------------
__global__ __launch_bounds__(512, 8) void mqa_attn_kernel(
    const bf16_t* __restrict__ qkv, const bf16_t* __restrict__ vtg,
    bf16_t* __restrict__ out)
{
  __shared__ bf16_t sh[20480];           // 40960 B
  // K[buf]  = sh + buf*4096           : [32][128]  keys x d   (swizzled ^r&7)
  // VT[buf] = sh + 8192 + buf*4096    : [128][32]  d x keys   (swizzled ^r&3)
  // P       = sh + 16384              : [128][32]  q x keys   (swizzled ^r&3)
  // O overlay over sh[0..17408) after the loop.

  const int tid  = threadIdx.x;
  const int wv   = tid >> 6;             // 0..7 : q-strip
  const int lane = tid & 63;
  const int quad = lane >> 4;
  const int c16  = lane & 15;
  const int h = blockIdx.y;
  const int b = blockIdx.z;
  const float qscale = 0.08838834764831845f * 1.4426950408889634f; // /sqrt(128)*log2e

  const bf16_t* kbase = qkv + (size_t)b * S_LEN * QKVN + HID;
  const bf16_t* vtb   = vtg + (size_t)b * HD * S_LEN;

  const int qh = ((int)blockIdx.x + h) & 15;
  const int Q  = b ? (15 - qh) : qh;     // balanced pairing across batch axis
  const int q0 = Q * 128;
  const int qrow = q0 + wv * 16 + c16;
  const int ntile = 4 * Q + 4;           // 32-key tiles to process

  const bf16_t* qp = qkv + ((size_t)(b * S_LEN + qrow)) * QKVN + h * HD;
  bf16x8 qf[4];
  #pragma unroll
  for (int ks = 0; ks < 4; ++ks) {
    bf16x8 t = *(const bf16x8*)(qp + ks * 32 + quad * 8);
    #pragma unroll
    for (int j = 0; j < 8; ++j) t[j] = (bf16_t)((float)t[j] * qscale);
    qf[ks] = t;
  }

  float m_q = NEG_BIG, l_q = 0.0f;
  f32x4 o[8] = {};

  // P addressing (dedicated region, wave-private rows, XOR chunk swizzle)
  const int prow = wv * 16 + c16;
  const int psw  = prow & 3;
  bf16_t* Pbase = sh + 16384 + (size_t)prow * 32;

  // DMA staging, 2 gld/thread: K = 512 chunks (32 rows x 16), V = 512
  // chunks (128 rows x 4). Slot c holds source chunk (c&mask)^(r&rm) of
  // its row -> reads apply the same involution. LDS dst wave-uniform.
  #define STAGE(bufi, kti) do {                                              \
    const bf16_t* kb_ = kbase + (size_t)(kti) * 32 * QKVN;                   \
    const bf16_t* vb_ = vtb + (kti) * 32;                                    \
    bf16_t* Kd_ = sh + (bufi) * 4096;                                        \
    bf16_t* Vd_ = sh + 8192 + (bufi) * 4096;                                 \
    {                                                                        \
      int r_ = tid >> 4, lc_ = (tid & 15) ^ (r_ & 7);                        \
      gld_lds16(kb_ + (size_t)r_ * QKVN + lc_ * 8, Kd_ + (tid & ~63) * 8);   \
    }                                                                        \
    {                                                                        \
      int r_ = tid >> 2, lc_ = (tid & 3) ^ (r_ & 3);                         \
      gld_lds16(vb_ + (size_t)r_ * S_LEN + lc_ * 8, Vd_ + (tid & ~63) * 8);  \
    }                                                                        \
  } while (0)

  STAGE(0, 0);
  int cur = 0;

  for (int kt = 0; kt < ntile; ++kt) {
    // __syncthreads = s_waitcnt vmcnt(0) lgkmcnt(0) + s_barrier: completes
    // buf[cur]'s DMA (issued one tile ago) AND rendezvous so the DMA
    // issued below may overwrite the buffer read last iteration.
    __syncthreads();
    if (kt + 1 < ntile) STAGE(cur ^ 1, kt + 1);

    const bf16_t* Kc = sh + cur * 4096;
    const bf16_t* Vc = sh + 8192 + cur * 4096;
    const bool wactive = (kt * 32) <= (q0 + wv * 16 + 15);
    if (wactive) {
      f32x4 sacc[2] = {};
      __builtin_amdgcn_s_setprio(1);
      #pragma unroll
      for (int mt = 0; mt < 2; ++mt) {
        int krow = mt * 16 + c16;
        #pragma unroll
        for (int ks = 0; ks < 4; ++ks) {
          bf16x8 kf = *(const bf16x8*)(Kc + krow * 128 +
                                       (((ks * 4 + quad) ^ (krow & 7)) << 3));
          sacc[mt] = __builtin_amdgcn_mfma_f32_16x16x32_bf16(kf, qf[ks], sacc[mt], 0, 0, 0);
        }
      }
      __builtin_amdgcn_s_setprio(0);

      float mx = NEG_BIG;
      if (kt * 32 + 31 > q0 + wv * 16) {   // diagonal tile for this wave
        #pragma unroll
        for (int mt = 0; mt < 2; ++mt) {
          #pragma unroll
          for (int r = 0; r < 4; ++r) {
            int key = kt * 32 + mt * 16 + quad * 4 + r;
            float v = sacc[mt][r];
            if (key > qrow) v = NEG_BIG;
            sacc[mt][r] = v;
            mx = fmaxf(mx, v);
          }
        }
      } else {
        #pragma unroll
        for (int mt = 0; mt < 2; ++mt) {
          #pragma unroll
          for (int r = 0; r < 4; ++r) mx = fmaxf(mx, sacc[mt][r]);
        }
      }
      mx = fmaxf(mx, __shfl_xor(mx, 16));
      mx = fmaxf(mx, __shfl_xor(mx, 32));

      // T13 defer-max: only rescale when the running max grew by >THR.
      if (__any(mx > m_q + RESCALE_THR)) {
        float mn = fmaxf(m_q, mx);
        float alpha = __builtin_exp2f(m_q - mn);
        m_q = mn;
        l_q *= alpha;
        #pragma unroll
        for (int mt8 = 0; mt8 < 8; ++mt8) {
          #pragma unroll
          for (int r = 0; r < 4; ++r) o[mt8][r] *= alpha;
        }
      }

      float rs = 0.f;
      #pragma unroll
      for (int mt = 0; mt < 2; ++mt) {
        #pragma unroll
        for (int r = 0; r < 4; ++r) {
          float pe = __builtin_exp2f(sacc[mt][r] - m_q);
          sacc[mt][r] = pe;
          rs += pe;
        }
      }
      rs += __shfl_xor(rs, 16);
      rs += __shfl_xor(rs, 32);
      l_q += rs;

      // P write (wave-private rows -> NO barrier): key = mt*16+quad*4+r
      // -> logical chunk 2*mt+(quad>>1), phys ^psw, half (quad&1)*4.
      #pragma unroll
      for (int mt = 0; mt < 2; ++mt) {
        bf16x4 pk;
        #pragma unroll
        for (int r = 0; r < 4; ++r) pk[r] = (bf16_t)sacc[mt][r];
        int ch = 2 * mt + (quad >> 1);
        *(bf16x4*)(Pbase + (((ch ^ psw) << 3) + (quad & 1) * 4)) = pk;
      }
      // P read: logical chunk = quad (keys quad*8+j), same involution.
      bf16x8 pf = *(const bf16x8*)(Pbase + (((quad ^ psw)) << 3));

      __builtin_amdgcn_s_setprio(1);
      #pragma unroll
      for (int mt8 = 0; mt8 < 8; ++mt8) {
        int vrow = mt8 * 16 + c16;
        bf16x8 vf = *(const bf16x8*)(Vc + vrow * 32 +
                                     ((quad ^ (vrow & 3)) << 3));
        o[mt8] = __builtin_amdgcn_mfma_f32_16x16x32_bf16(vf, pf, o[mt8], 0, 0, 0);
      }
      __builtin_amdgcn_s_setprio(0);
    }
    cur ^= 1;
  }
  #undef STAGE

  // ---- normalize + coalesced store via O overlay ----
  __syncthreads();   // all K/VT/P reads done; pool reusable as O
  float inv = 1.0f / fmaxf(l_q, 1e-20f);
  bf16_t* Osh = sh;  // [128][136] = 17408 elems <= 20480
  #pragma unroll
  for (int mt8 = 0; mt8 < 8; ++mt8) {
    bf16x4 pk;
    #pragma unroll
    for (int r = 0; r < 4; ++r) pk[r] = (bf16_t)(o[mt8][r] * inv);
    *(bf16x4*)(&Osh[(size_t)prow * 136 + mt8 * 16 + quad * 4]) = pk;
  }
  // rows are wave-private; compiler inserts the lgkmcnt for the DS RAW
  int ql = lane >> 2, dc = lane & 3;
  #pragma unroll
  for (int i = 0; i < 4; ++i) {
    bf16x8 v = *(const bf16x8*)(&Osh[(size_t)(wv * 16 + ql) * 136 + dc * 8 + i * 32]);
    *(bf16x8*)(out + ((size_t)(b * S_LEN + q0 + wv * 16 + ql)) * HID
                   + h * HD + dc * 8 + i * 32) = v;
  }
}

extern "C" void kernel_launch(void* const* d_in, const int* in_sizes, int n_in,
                              void* d_out, int out_size, void* d_ws, size_t ws_size,
                              hipStream_t stream) {
  const float* hidden_f   = (const float*)d_in[0];
  // d_in[1] = attention_mask (deterministic causal) -- ignored
  const float* c_attn_w_f = (const float*)d_in[2];
  const float* c_attn_b_f = (const float*)d_in[3];
  const float* c_proj_w_f = (const float*)d_in[4];
  const float* c_proj_b_f = (const float*)d_in[5];
  float* out = (float*)d_out;

  const int M = 2 * S_LEN;                 // 4096
  const int nH  = M * HID;
  const int nWq = HID * QKVN;
  const int nWp = HID * HID;

  bf16_t* hbf   = (bf16_t*)d_ws;
  bf16_t* wqT   = hbf  + nH;               // WT_qkv [2304][2048]
  bf16_t* wpT   = wqT  + nWq;              // WT_proj[2048][2048]
  bf16_t* qkv   = wpT  + nWp;              // [4096][2304]
  bf16_t* attn  = qkv  + (size_t)M * QKVN; // [4096][2048]
  bf16_t* vtg   = attn + (size_t)M * HID;  // V^T [2][128][2048]

  // fused prep: cvt (8192 blocks) + W_qkv^T (2304) + W_proj^T (2048)
  prep_kernel<<<12544, 256, 0, stream>>>(hidden_f, hbf, c_attn_w_f, wqT,
                                         c_proj_w_f, wpT);

  dim3 g1(QKVN / 64, M / 128);             // 36 x 32 = 1152 blocks
  gemm_bias_kernel<bf16_t><<<g1, 256, 0, stream>>>(hbf, wqT, c_attn_b_f, qkv,
                                                   HID, HID, QKVN);

  dim3 gv(S_LEN / 16, 2);
  vt_extract_kernel<<<gv, 256, 0, stream>>>(qkv, vtg);

  dim3 g2(16, NH, 2);
  mqa_attn_kernel<<<g2, 512, 0, stream>>>(qkv, vtg, attn);

  dim3 g3(HID / 64, M / 128);              // 32 x 32 = 1024 blocks
  gemm_bias_kernel<float><<<g3, 256, 0, stream>>>(attn, wpT, c_proj_b_f, out,
                                                  HID, HID, HID);
}

// Round 13
// 290.357 us; speedup vs baseline: 1.8908x; 1.8908x over previous
//
#include <hip/hip_runtime.h>
#include <hip/hip_bf16.h>

typedef __bf16 bf16_t;
typedef __bf16 bf16x8 __attribute__((ext_vector_type(8)));
typedef __bf16 bf16x4 __attribute__((ext_vector_type(4)));
typedef float f32x4 __attribute__((ext_vector_type(4)));

#define S_LEN 2048
#define HID   2048
#define NH    16
#define HD    128
#define QKVN  2304   // 2048 + 2*128
#define NEG_BIG (-30000.0f)
#define RESCALE_THR 8.0f

// direct global->LDS DMA, 16B per lane. lds dst must be the WAVE-UNIFORM base;
// HW adds lane*16 itself (m104). No LDS padding allowed in the covered range.
__device__ __forceinline__ void gld_lds16(const bf16_t* g, bf16_t* l) {
  __builtin_amdgcn_global_load_lds(
      (const __attribute__((address_space(1))) void*)((const void*)g),
      (__attribute__((address_space(3))) void*)((void*)l), 16, 0, 0);
}

// ---------------------------------------------------------------------------
// Fused prep: fp32->bf16 downcast of hidden states + both weight transposes.
// (verified round 10)
// ---------------------------------------------------------------------------
__device__ __forceinline__ void transpose_cvt_body(
    const float* __restrict__ in, bf16_t* __restrict__ out,
    int K, int N, int bx, int by, int tid)
{
  int nc = tid & 63;
  int kg = tid >> 6;
  int n  = bx * 64 + nc;
  int kb = by * 32 + kg * 8;
  bf16x8 v;
  #pragma unroll
  for (int i = 0; i < 8; ++i) v[i] = (bf16_t)in[(size_t)(kb + i) * N + n];
  *(bf16x8*)(out + (size_t)n * K + kb) = v;
}

__global__ __launch_bounds__(256) void prep_kernel(
    const float* __restrict__ hidden, bf16_t* __restrict__ hbf,
    const float* __restrict__ wq, bf16_t* __restrict__ wqT,
    const float* __restrict__ wp, bf16_t* __restrict__ wpT)
{
  const int id  = blockIdx.x;
  const int tid = threadIdx.x;
  if (id < 8192) {
    int i = (id * 256 + tid) * 4;
    float4 v = *(const float4*)(hidden + i);
    bf16x4 o;
    o[0] = (bf16_t)v.x; o[1] = (bf16_t)v.y; o[2] = (bf16_t)v.z; o[3] = (bf16_t)v.w;
    *(bf16x4*)(hbf + i) = o;
  } else if (id < 8192 + 2304) {
    int id2 = id - 8192;
    transpose_cvt_body(wq, wqT, HID, QKVN, id2 % 36, id2 / 36, tid);
  } else {
    int id2 = id - 10496;
    transpose_cvt_body(wp, wpT, HID, HID, id2 % 32, id2 / 32, tid);
  }
}

// ---------------------------------------------------------------------------
// Extract V^T from qkv: vtg[b][d][s] = qkv[b*S+s][2176+d].
// (verified; r10 proved epilogue scatter-fusion is worse than this kernel)
// ---------------------------------------------------------------------------
__global__ __launch_bounds__(256) void vt_extract_kernel(
    const bf16_t* __restrict__ qkv, bf16_t* __restrict__ vtg)
{
  int d  = threadIdx.x & 127;
  int sg = threadIdx.x >> 7;
  int b  = blockIdx.y;
  int s8 = blockIdx.x * 2 + sg;
  bf16x8 v;
  #pragma unroll
  for (int i = 0; i < 8; ++i)
    v[i] = qkv[((size_t)(b * S_LEN + s8 * 8 + i)) * QKVN + HID + HD + d];
  *(bf16x8*)(vtg + ((size_t)(b * HD + d)) * S_LEN + s8 * 8) = v;
}

// ---------------------------------------------------------------------------
// GEMM: C[M,N] = A[M,K] @ WT^T + bias (WT pre-transposed [N][K]).
// 128x128 C-tile, BK=64, 8 waves as 2x4 (wave 64x32, acc[4][2]) — the r9
// configuration, best verified GEMM this session (4 waves/SIMD; dropped the
// GEMMs below attention). T1 XCD swizzle (r5). 1-barrier double-buffered
// gld_lds DMA schedule (r7). r11's 128x64 4-wave re-tile was ~4 us worse
// and is reverted; r12's occupancy push is VGPR-blocked (see attn note).
// ---------------------------------------------------------------------------
template <typename OutT>
__global__ __launch_bounds__(512, 4) void gemm_bias_kernel(
    const bf16_t* __restrict__ A, const bf16_t* __restrict__ WT,
    const float* __restrict__ bias, OutT* __restrict__ C,
    int K, int lda, int ldc)
{
  __shared__ bf16_t Ash[2 * 128 * 64];   // [buf][m][k] swizzled, NO padding
  __shared__ bf16_t Bsh[2 * 128 * 64];   // [buf][n][k] swizzled, NO padding

  const int tid  = threadIdx.x;
  const int wave = tid >> 6;
  const int lane = tid & 63;
  const int quad = lane >> 4;
  const int c16  = lane & 15;
  const int wm = wave >> 2;          // 0..1 : 64-row half
  const int wn = wave & 3;           // 0..3 : 32-col quarter

  // T1 XCD swizzle: id -> (id%8)*cpx + id/8, bijective when nwg%8==0.
  int id  = (int)(blockIdx.y * gridDim.x + blockIdx.x);
  int nwg = (int)(gridDim.x * gridDim.y);
  int swz = (nwg & 7) ? id : ((id & 7) * (nwg >> 3) + (id >> 3));
  const int n0 = (swz % (int)gridDim.x) * 128;
  const int m0 = (swz / (int)gridDim.x) * 128;

  f32x4 acc[4][2] = {};

  // 1024 16B-chunks per operand tile; wave stages [wave*128, wave*128+128).
  // Slot c holds global chunk (row=c>>3, kc=(c^row)&7) — XOR chunk fetch,
  // matching the swizzled read below. LDS dst is the wave-uniform base.
  #define GSTAGE(bufi, k0v) do {                                             \
    bf16_t* Ad_ = Ash + (bufi) * 8192;                                       \
    bf16_t* Bd_ = Bsh + (bufi) * 8192;                                       \
    _Pragma("unroll")                                                        \
    for (int j_ = 0; j_ < 2; ++j_) {                                         \
      int cbase_ = wave * 128 + j_ * 64;                                     \
      int c_ = cbase_ + lane;                                                \
      int row_ = c_ >> 3;                                                    \
      int kcl_ = (c_ ^ row_) & 7;                                            \
      gld_lds16(A  + (size_t)(m0 + row_) * lda + (k0v) + kcl_ * 8,           \
                Ad_ + cbase_ * 8);                                           \
      gld_lds16(WT + (size_t)(n0 + row_) * K   + (k0v) + kcl_ * 8,           \
                Bd_ + cbase_ * 8);                                           \
    }                                                                        \
  } while (0)

  GSTAGE(0, 0);
  int cur = 0;

  for (int k0 = 0; k0 < K; k0 += 64) {
    // __syncthreads = s_waitcnt vmcnt(0) lgkmcnt(0) + s_barrier: completes
    // buf[cur]'s DMA (issued one K-step ago) AND rendezvous so the DMA
    // issued below may overwrite the buffer read last step.
    __syncthreads();
    if (k0 + 64 < K) GSTAGE(cur ^ 1, k0 + 64);

    const bf16_t* Ac = Ash + cur * 8192;
    const bf16_t* Bc = Bsh + cur * 8192;
    #pragma unroll
    for (int kk = 0; kk < 2; ++kk) {
      bf16x8 af[4], bfr[2];
      #pragma unroll
      for (int rb = 0; rb < 4; ++rb) {
        int row = wm * 64 + rb * 16 + c16;
        int kcp = ((kk * 4 + quad) ^ row) & 7;
        af[rb] = *(const bf16x8*)(Ac + row * 64 + kcp * 8);
      }
      #pragma unroll
      for (int nt = 0; nt < 2; ++nt) {
        int row = wn * 32 + nt * 16 + c16;
        int kcp = ((kk * 4 + quad) ^ row) & 7;
        bfr[nt] = *(const bf16x8*)(Bc + row * 64 + kcp * 8);
      }
      #pragma unroll
      for (int rb = 0; rb < 4; ++rb)
        #pragma unroll
        for (int nt = 0; nt < 2; ++nt)
          acc[rb][nt] = __builtin_amdgcn_mfma_f32_16x16x32_bf16(af[rb], bfr[nt],
                                                                acc[rb][nt], 0, 0, 0);
    }
    cur ^= 1;
  }
  #undef GSTAGE

  #pragma unroll
  for (int nt = 0; nt < 2; ++nt) {
    int col = n0 + wn * 32 + nt * 16 + c16;
    float bv = bias[col];
    #pragma unroll
    for (int rb = 0; rb < 4; ++rb) {
      int rbase = m0 + wm * 64 + rb * 16 + quad * 4;
      #pragma unroll
      for (int r = 0; r < 4; ++r)
        C[(size_t)(rbase + r) * ldc + col] = (OutT)(acc[rb][nt][r] + bv);
    }
  }
}

// ---------------------------------------------------------------------------
// Causal MQA attention, S^T formulation, QBLK=128, 8 waves, KVBLK=64.
// REVERTED to the r7/r11 verified version (71.5-72.4 us across 3 runs).
//
// r12 post-mortem (attn 313 us): launch_bounds(512,8) capped VGPR at 64 <
// live state (~100: o[8]=32 + qf=16 + sacc + addressing) -> compiler
// allocated 32 arch-VGPRs and spilled O to scratch (WRITE_SIZE 16->383 MB).
// The 4-blocks/CU occupancy push is VGPR-BLOCKED for this algorithm, not
// mis-tuned: 8 waves/SIMD requires <=64 VGPR, which cannot hold the
// per-thread O/Q state. 2 blocks/CU (4 waves/SIMD) is this structure's
// occupancy ceiling. Parked permanently.
// ---------------------------------------------------------------------------
__global__ __launch_bounds__(512, 4) void mqa_attn_kernel(
    const bf16_t* __restrict__ qkv, const bf16_t* __restrict__ vtg,
    bf16_t* __restrict__ out)
{
  __shared__ bf16_t sh[40960];           // 81920 B
  // K[buf]  = sh + buf*8192           : [64][128]  keys x d   (swizzled)
  // VT[buf] = sh + 16384 + buf*8192   : [128][64]  d x keys   (swizzled)
  // P       = sh + 32768              : [128][64]  q x keys   (swizzled)
  // O overlay over sh[0..17408) after the loop.

  const int tid  = threadIdx.x;
  const int wv   = tid >> 6;             // 0..7 : q-strip
  const int lane = tid & 63;
  const int quad = lane >> 4;
  const int c16  = lane & 15;
  const int h = blockIdx.y;
  const int b = blockIdx.z;
  const float qscale = 0.08838834764831845f * 1.4426950408889634f; // /sqrt(128)*log2e

  const bf16_t* kbase = qkv + (size_t)b * S_LEN * QKVN + HID;
  const bf16_t* vtb   = vtg + (size_t)b * HD * S_LEN;

  const int qh = ((int)blockIdx.x + h) & 15;
  const int Q  = b ? (15 - qh) : qh;     // balanced pairing across batch axis
  const int q0 = Q * 128;
  const int qrow = q0 + wv * 16 + c16;
  const int ntile = 2 * Q + 2;           // 64-key tiles to process

  const bf16_t* qp = qkv + ((size_t)(b * S_LEN + qrow)) * QKVN + h * HD;
  bf16x8 qf[4];
  #pragma unroll
  for (int ks = 0; ks < 4; ++ks) {
    bf16x8 t = *(const bf16x8*)(qp + ks * 32 + quad * 8);
    #pragma unroll
    for (int j = 0; j < 8; ++j) t[j] = (bf16_t)((float)t[j] * qscale);
    qf[ks] = t;
  }

  float m_q = NEG_BIG, l_q = 0.0f;
  f32x4 o[8] = {};

  // P addressing (dedicated region, wave-private rows, XOR chunk swizzle)
  const int prow = wv * 16 + c16;
  const int rsw  = prow & 7;
  bf16_t* Pbase = sh + 32768 + (size_t)prow * 64;

  // DMA staging: K = 1024 chunks (64 rows x 16), VT = 1024 chunks (128 x 8).
  // Slot c holds source chunk (c&mask)^(row&7) of its row -> reads below
  // apply the same involution. LDS dst is the wave-uniform base (c & ~63).
  #define STAGE(bufi, kti) do {                                              \
    const bf16_t* kb_ = kbase + (size_t)(kti) * 64 * QKVN;                   \
    const bf16_t* vb_ = vtb + (kti) * 64;                                    \
    bf16_t* Kd_ = sh + (bufi) * 8192;                                        \
    bf16_t* Vd_ = sh + 16384 + (bufi) * 8192;                                \
    _Pragma("unroll")                                                        \
    for (int i_ = 0; i_ < 2; ++i_) {                                         \
      int c_ = tid + i_ * 512;                                               \
      int r_ = c_ >> 4, lc_ = (c_ & 15) ^ (r_ & 7);                          \
      gld_lds16(kb_ + (size_t)r_ * QKVN + lc_ * 8, Kd_ + (c_ & ~63) * 8);    \
    }                                                                        \
    _Pragma("unroll")                                                        \
    for (int i_ = 0; i_ < 2; ++i_) {                                         \
      int c_ = tid + i_ * 512;                                               \
      int r_ = c_ >> 3, lc_ = (c_ & 7) ^ (r_ & 7);                           \
      gld_lds16(vb_ + (size_t)r_ * S_LEN + lc_ * 8, Vd_ + (c_ & ~63) * 8);   \
    }                                                                        \
  } while (0)

  STAGE(0, 0);
  int cur = 0;

  for (int kt = 0; kt < ntile; ++kt) {
    // HIP __syncthreads = s_waitcnt vmcnt(0) lgkmcnt(0) + s_barrier:
    // completes buf[cur]'s DMA (issued one tile ago) AND rendezvous so the
    // DMA issued below may overwrite the buffer read last iteration.
    __syncthreads();
    if (kt + 1 < ntile) STAGE(cur ^ 1, kt + 1);

    const bf16_t* Kc = sh + cur * 8192;
    const bf16_t* Vc = sh + 16384 + cur * 8192;
    const bool wactive = (kt * 64) <= (q0 + wv * 16 + 15);
    if (wactive) {
      f32x4 sacc[4] = {};
      __builtin_amdgcn_s_setprio(1);
      #pragma unroll
      for (int mt = 0; mt < 4; ++mt) {
        int krow = mt * 16 + c16;
        #pragma unroll
        for (int ks = 0; ks < 4; ++ks) {
          bf16x8 kf = *(const bf16x8*)(Kc + krow * 128 +
                                       (((ks * 4 + quad) ^ (krow & 7)) << 3));
          sacc[mt] = __builtin_amdgcn_mfma_f32_16x16x32_bf16(kf, qf[ks], sacc[mt], 0, 0, 0);
        }
      }
      __builtin_amdgcn_s_setprio(0);

      float mx = NEG_BIG;
      if (kt * 64 + 63 > q0 + wv * 16) {   // diagonal tile for this wave
        #pragma unroll
        for (int mt = 0; mt < 4; ++mt) {
          #pragma unroll
          for (int r = 0; r < 4; ++r) {
            int key = kt * 64 + mt * 16 + quad * 4 + r;
            float v = sacc[mt][r];
            if (key > qrow) v = NEG_BIG;
            sacc[mt][r] = v;
            mx = fmaxf(mx, v);
          }
        }
      } else {
        #pragma unroll
        for (int mt = 0; mt < 4; ++mt) {
          #pragma unroll
          for (int r = 0; r < 4; ++r) mx = fmaxf(mx, sacc[mt][r]);
        }
      }
      mx = fmaxf(mx, __shfl_xor(mx, 16));
      mx = fmaxf(mx, __shfl_xor(mx, 32));

      // T13 defer-max: only rescale when the running max grew by >THR.
      if (__any(mx > m_q + RESCALE_THR)) {
        float mn = fmaxf(m_q, mx);
        float alpha = __builtin_exp2f(m_q - mn);
        m_q = mn;
        l_q *= alpha;
        #pragma unroll
        for (int mt8 = 0; mt8 < 8; ++mt8) {
          #pragma unroll
          for (int r = 0; r < 4; ++r) o[mt8][r] *= alpha;
        }
      }

      float rs = 0.f;
      #pragma unroll
      for (int mt = 0; mt < 4; ++mt) {
        #pragma unroll
        for (int r = 0; r < 4; ++r) {
          float pe = __builtin_exp2f(sacc[mt][r] - m_q);
          sacc[mt][r] = pe;
          rs += pe;
        }
      }
      rs += __shfl_xor(rs, 16);
      rs += __shfl_xor(rs, 32);
      l_q += rs;

      // P write (wave-private rows -> NO barrier): key = mt*16+quad*4+r
      // -> logical chunk 2*mt+(quad>>1), phys ^rsw, half (quad&1)*4.
      #pragma unroll
      for (int mt = 0; mt < 4; ++mt) {
        bf16x4 pk;
        #pragma unroll
        for (int r = 0; r < 4; ++r) pk[r] = (bf16_t)sacc[mt][r];
        int ch = 2 * mt + (quad >> 1);
        *(bf16x4*)(Pbase + (((ch ^ rsw) << 3) + (quad & 1) * 4)) = pk;
      }
      // P read: logical chunk 4*kh+quad, same involution, 16B-aligned.
      bf16x8 pf[2];
      #pragma unroll
      for (int kh = 0; kh < 2; ++kh)
        pf[kh] = *(const bf16x8*)(Pbase + (((4 * kh + quad) ^ rsw) << 3));

      __builtin_amdgcn_s_setprio(1);
      #pragma unroll
      for (int mt8 = 0; mt8 < 8; ++mt8) {
        int vrow = mt8 * 16 + c16;
        #pragma unroll
        for (int kh = 0; kh < 2; ++kh) {
          bf16x8 vf = *(const bf16x8*)(Vc + vrow * 64 +
                                       (((kh * 4 + quad) ^ (vrow & 7)) << 3));
          o[mt8] = __builtin_amdgcn_mfma_f32_16x16x32_bf16(vf, pf[kh], o[mt8], 0, 0, 0);
        }
      }
      __builtin_amdgcn_s_setprio(0);
    }
    cur ^= 1;
  }
  #undef STAGE

  // ---- normalize + coalesced store via O overlay ----
  __syncthreads();   // all K/VT/P reads done; pool reusable as O
  float inv = 1.0f / fmaxf(l_q, 1e-20f);
  bf16_t* Osh = sh;  // [128][136]
  #pragma unroll
  for (int mt8 = 0; mt8 < 8; ++mt8) {
    bf16x4 pk;
    #pragma unroll
    for (int r = 0; r < 4; ++r) pk[r] = (bf16_t)(o[mt8][r] * inv);
    *(bf16x4*)(&Osh[(size_t)prow * 136 + mt8 * 16 + quad * 4]) = pk;
  }
  // rows are wave-private; compiler inserts the lgkmcnt for the DS RAW
  int ql = lane >> 2, dc = lane & 3;
  #pragma unroll
  for (int i = 0; i < 4; ++i) {
    bf16x8 v = *(const bf16x8*)(&Osh[(size_t)(wv * 16 + ql) * 136 + dc * 8 + i * 32]);
    *(bf16x8*)(out + ((size_t)(b * S_LEN + q0 + wv * 16 + ql)) * HID
                   + h * HD + dc * 8 + i * 32) = v;
  }
}

extern "C" void kernel_launch(void* const* d_in, const int* in_sizes, int n_in,
                              void* d_out, int out_size, void* d_ws, size_t ws_size,
                              hipStream_t stream) {
  const float* hidden_f   = (const float*)d_in[0];
  // d_in[1] = attention_mask (deterministic causal) -- ignored
  const float* c_attn_w_f = (const float*)d_in[2];
  const float* c_attn_b_f = (const float*)d_in[3];
  const float* c_proj_w_f = (const float*)d_in[4];
  const float* c_proj_b_f = (const float*)d_in[5];
  float* out = (float*)d_out;

  const int M = 2 * S_LEN;                 // 4096
  const int nH  = M * HID;
  const int nWq = HID * QKVN;
  const int nWp = HID * HID;

  bf16_t* hbf   = (bf16_t*)d_ws;
  bf16_t* wqT   = hbf  + nH;               // WT_qkv [2304][2048]
  bf16_t* wpT   = wqT  + nWq;              // WT_proj[2048][2048]
  bf16_t* qkv   = wpT  + nWp;              // [4096][2304]
  bf16_t* attn  = qkv  + (size_t)M * QKVN; // [4096][2048]
  bf16_t* vtg   = attn + (size_t)M * HID;  // V^T [2][128][2048]

  // fused prep: cvt (8192 blocks) + W_qkv^T (2304) + W_proj^T (2048)
  prep_kernel<<<12544, 256, 0, stream>>>(hidden_f, hbf, c_attn_w_f, wqT,
                                         c_proj_w_f, wpT);

  dim3 g1(QKVN / 128, M / 128);            // 18 x 32 = 576 blocks
  gemm_bias_kernel<bf16_t><<<g1, 512, 0, stream>>>(hbf, wqT, c_attn_b_f, qkv,
                                                   HID, HID, QKVN);

  dim3 gv(S_LEN / 16, 2);
  vt_extract_kernel<<<gv, 256, 0, stream>>>(qkv, vtg);

  dim3 g2(16, NH, 2);
  mqa_attn_kernel<<<g2, 512, 0, stream>>>(qkv, vtg, attn);

  dim3 g3(HID / 128, M / 128);             // 16 x 32 = 512 blocks
  gemm_bias_kernel<float><<<g3, 512, 0, stream>>>(attn, wpT, c_proj_b_f, out,
                                                  HID, HID, HID);
}